// Round 1
// baseline (154.548 us; speedup 1.0000x reference)
//
#include <hip/hip_runtime.h>
#include <math.h>

// Distral per-task MLP: 32769 heads, each h = relu(W1[3->100] x + b1),
// p = softmax(W2[100->5] h + b2).  Pure HBM-bound: ~3.6 KB read per head,
// ~119 MB total.  One wave64 per head; layer-1 activations stay in the
// lane registers that layer-2 consumes (no LDS), butterfly shuffle-reduce
// for the 5 logits.

#define N_HEADS 32769
#define IN_DIM  3
#define HID     100
#define OUT     5

__global__ __launch_bounds__(256) void distral_kernel(
    const float* __restrict__ x,
    const float* __restrict__ W1,
    const float* __restrict__ b1,
    const float* __restrict__ W2,
    const float* __restrict__ b2,
    float* __restrict__ out)
{
    const int wave = threadIdx.x >> 6;
    const int lane = threadIdx.x & 63;
    const int head = blockIdx.x * 4 + wave;
    if (head >= N_HEADS) return;

    // x is tiny (12 B/head); uniform-per-wave broadcast load via cache.
    const float x0 = x[head * 3 + 0];
    const float x1 = x[head * 3 + 1];
    const float x2 = x[head * 3 + 2];

    const float* W1h = W1 + (size_t)head * (HID * IN_DIM);
    const float* b1h = b1 + (size_t)head * HID;
    const float* W2h = W2 + (size_t)head * (OUT * HID);

    // ---- layer 1: lane l computes h[l] and h[l+64] (HID=100) ----
    float h0, h1 = 0.0f;
    {
        const int j = lane;
        const float a0 = W1h[j * 3 + 0];
        const float a1 = W1h[j * 3 + 1];
        const float a2 = W1h[j * 3 + 2];
        h0 = fmaxf(fmaf(a0, x0, fmaf(a1, x1, fmaf(a2, x2, b1h[j]))), 0.0f);
    }
    const int j2 = lane + 64;
    const bool has2 = (j2 < HID);   // lanes 0..35
    if (has2) {
        const float a0 = W1h[j2 * 3 + 0];
        const float a1 = W1h[j2 * 3 + 1];
        const float a2 = W1h[j2 * 3 + 2];
        h1 = fmaxf(fmaf(a0, x0, fmaf(a1, x1, fmaf(a2, x2, b1h[j2]))), 0.0f);
    }

    // ---- layer 2: per-lane partial dot for each of the 5 outputs ----
    float acc[OUT];
#pragma unroll
    for (int o = 0; o < OUT; ++o) {
        float p = W2h[o * HID + lane] * h0;            // 64 consecutive floats: coalesced
        if (has2) p = fmaf(W2h[o * HID + j2], h1, p);  // 36-float tail
        acc[o] = p;
    }

    // butterfly reduce over the full 64-lane wave
#pragma unroll
    for (int off = 32; off > 0; off >>= 1) {
#pragma unroll
        for (int o = 0; o < OUT; ++o)
            acc[o] += __shfl_xor(acc[o], off, 64);
    }

    // all lanes now hold the 5 full logits; add bias, softmax in registers
    float m = -INFINITY;
#pragma unroll
    for (int o = 0; o < OUT; ++o) {
        acc[o] += b2[head * OUT + o];
        m = fmaxf(m, acc[o]);
    }
    float s = 0.0f;
#pragma unroll
    for (int o = 0; o < OUT; ++o) {
        acc[o] = __expf(acc[o] - m);
        s += acc[o];
    }
    const float inv = 1.0f / s;

    // lanes 0..4 store the 5 outputs (coalesced 20 B)
    if (lane < OUT) {
        float v = (lane == 0) ? acc[0]
                : (lane == 1) ? acc[1]
                : (lane == 2) ? acc[2]
                : (lane == 3) ? acc[3]
                :               acc[4];
        out[(size_t)head * OUT + lane] = v * inv;
    }
}

extern "C" void kernel_launch(void* const* d_in, const int* in_sizes, int n_in,
                              void* d_out, int out_size, void* d_ws, size_t ws_size,
                              hipStream_t stream) {
    const float* x  = (const float*)d_in[0];
    const float* W1 = (const float*)d_in[1];
    const float* b1 = (const float*)d_in[2];
    const float* W2 = (const float*)d_in[3];
    const float* b2 = (const float*)d_in[4];
    float* out = (float*)d_out;

    const int heads_per_block = 4;                       // 4 waves * 64 lanes = 256 threads
    const int blocks = (N_HEADS + heads_per_block - 1) / heads_per_block;
    distral_kernel<<<blocks, 256, 0, stream>>>(x, W1, b1, W2, b2, out);
}

// Round 2
// 142.313 us; speedup vs baseline: 1.0860x; 1.0860x over previous
//
#include <hip/hip_runtime.h>
#include <math.h>

// Distral per-task MLP: 32769 heads, h = relu(W1[3->100] x + b1),
// p = softmax(W2[100->5] h + b2).  ~3.6 KB read per head, ~119 MB total.
//
// R2: latency-bound fix. R1 (VGPR=12) serialized ~19 narrow dword loads per
// wave -> chain of dependent L3-latency waits, 1.3 TB/s. Now each wave DMAs
// its whole head (W1|b1|W2 = 900 floats, all 16B-aligned strides) into LDS
// with 5 global_load_lds dwordx4 instructions issued back-to-back, waits
// once at the block barrier, then computes from LDS.

#define N_HEADS 32769
#define HID     100
#define OUT     5

#define HEADS_PER_BLOCK 4            // 4 waves x 64 lanes = 256 threads
#define FLOATS_PER_HEAD 900          // W1 300 | b1 100 | W2 500
#define LDS_B1 300                   // float offsets inside a head region
#define LDS_W2 400

#define GLOBAL_AS __attribute__((address_space(1)))
#define LDS_AS    __attribute__((address_space(3)))

static __device__ __forceinline__ void async_copy16(const void* g, void* l) {
    // 16B per lane: global (base + lane*16) -> LDS (uniform base + lane*16)
    __builtin_amdgcn_global_load_lds((const GLOBAL_AS void*)g, (LDS_AS void*)l,
                                     16, 0, 0);
}

__global__ __launch_bounds__(256) void distral_kernel(
    const float* __restrict__ x,
    const float* __restrict__ W1,
    const float* __restrict__ b1,
    const float* __restrict__ W2,
    const float* __restrict__ b2,
    float* __restrict__ out)
{
    __shared__ float lds[HEADS_PER_BLOCK * FLOATS_PER_HEAD];   // 14400 B

    const int wave = threadIdx.x >> 6;
    const int lane = threadIdx.x & 63;
    const int head = blockIdx.x * HEADS_PER_BLOCK + wave;
    const bool valid = (head < N_HEADS);

    float* region = lds + wave * FLOATS_PER_HEAD;

    float x0 = 0.f, x1 = 0.f, x2 = 0.f;
    float b2v[OUT] = {0.f, 0.f, 0.f, 0.f, 0.f};

    if (valid) {
        // --- stage W1 (75 f4), b1 (25 f4), W2 (125 f4) into LDS ---
        // All global bases 16B-aligned: head*1200 / head*400 / head*2000.
        const float* W1h = W1 + (size_t)head * 300;
        const float* b1h = b1 + (size_t)head * 100;
        const float* W2h = W2 + (size_t)head * 500;

        async_copy16(W1h + 4 * lane,            region);                 // f4 0..63
        if (lane < 11)
            async_copy16(W1h + 256 + 4 * lane,  region + 256);           // f4 64..74
        if (lane < 25)
            async_copy16(b1h + 4 * lane,        region + LDS_B1);        // 25 f4
        async_copy16(W2h + 4 * lane,            region + LDS_W2);        // f4 0..63
        if (lane < 61)
            async_copy16(W2h + 256 + 4 * lane,  region + LDS_W2 + 256);  // f4 64..124

        // small operands into registers while the DMA is in flight
        x0 = x[head * 3 + 0];
        x1 = x[head * 3 + 1];
        x2 = x[head * 3 + 2];
#pragma unroll
        for (int o = 0; o < OUT; ++o) b2v[o] = b2[head * OUT + o];
    }

    __syncthreads();   // drains vmcnt(0): LDS-DMA complete for all waves

    if (valid) {
        // ---- layer 1 from LDS: lane computes h[lane] and h[lane+64] ----
        const bool has2 = (lane < HID - 64);   // lanes 0..35
        float h0, h1 = 0.0f;
        {
            const float* r = region + 3 * lane;
            h0 = fmaxf(fmaf(r[0], x0, fmaf(r[1], x1, fmaf(r[2], x2,
                       region[LDS_B1 + lane]))), 0.0f);
        }
        if (has2) {
            const float* r = region + 3 * (lane + 64);
            h1 = fmaxf(fmaf(r[0], x0, fmaf(r[1], x1, fmaf(r[2], x2,
                       region[LDS_B1 + lane + 64]))), 0.0f);
        }

        // ---- layer 2 from LDS: per-lane partials for the 5 outputs ----
        float acc[OUT];
#pragma unroll
        for (int o = 0; o < OUT; ++o) {
            float p = region[LDS_W2 + o * HID + lane] * h0;
            if (has2) p = fmaf(region[LDS_W2 + o * HID + 64 + lane], h1, p);
            acc[o] = p;
        }

        // butterfly reduce across the 64-lane wave
#pragma unroll
        for (int off = 32; off > 0; off >>= 1) {
#pragma unroll
            for (int o = 0; o < OUT; ++o)
                acc[o] += __shfl_xor(acc[o], off, 64);
        }

        // softmax in registers (all lanes redundantly)
        float m = -INFINITY;
#pragma unroll
        for (int o = 0; o < OUT; ++o) {
            acc[o] += b2v[o];
            m = fmaxf(m, acc[o]);
        }
        float s = 0.0f;
#pragma unroll
        for (int o = 0; o < OUT; ++o) {
            acc[o] = __expf(acc[o] - m);
            s += acc[o];
        }
        const float inv = 1.0f / s;

        if (lane < OUT) {
            float v = (lane == 0) ? acc[0]
                    : (lane == 1) ? acc[1]
                    : (lane == 2) ? acc[2]
                    : (lane == 3) ? acc[3]
                    :               acc[4];
            out[(size_t)head * OUT + lane] = v * inv;
        }
    }
}

extern "C" void kernel_launch(void* const* d_in, const int* in_sizes, int n_in,
                              void* d_out, int out_size, void* d_ws, size_t ws_size,
                              hipStream_t stream) {
    const float* x  = (const float*)d_in[0];
    const float* W1 = (const float*)d_in[1];
    const float* b1 = (const float*)d_in[2];
    const float* W2 = (const float*)d_in[3];
    const float* b2 = (const float*)d_in[4];
    float* out = (float*)d_out;

    const int blocks = (N_HEADS + HEADS_PER_BLOCK - 1) / HEADS_PER_BLOCK;
    distral_kernel<<<blocks, 256, 0, stream>>>(x, W1, b1, W2, b2, out);
}